// Round 15
// baseline (109.244 us; speedup 1.0000x reference)
//
#include <hip/hip_runtime.h>
#include <hip/hip_bf16.h>
#include <math.h>

typedef _Float16 half8 __attribute__((ext_vector_type(8)));
typedef _Float16 half4v __attribute__((ext_vector_type(4)));
typedef __fp16 fp16x2 __attribute__((ext_vector_type(2)));
typedef float f32x4 __attribute__((ext_vector_type(4)));
typedef float f32x16 __attribute__((ext_vector_type(16)));

#define D 128
#define SQ 8192
#define SKV 8192
#define BQ 128    // q-rows per block (4 waves x 32)
#define BKV 32
#define LOG2E 1.4426950408889634f
#define DEFER_THR 11.5417f   // 8 * log2(e); P <= 2^11.54 ~ 2981 < f16 max

__device__ __forceinline__ ushort f2bf(float x) {
  union { float f; unsigned u; } v; v.f = x;
  unsigned r = v.u + 0x7fffu + ((v.u >> 16) & 1u);
  return (ushort)(r >> 16);
}
__device__ __forceinline__ float bf2f(ushort h) {
  union { unsigned u; float f; } v; v.u = ((unsigned)h) << 16;
  return v.f;
}
__device__ __forceinline__ unsigned cvtpk_bf(float a, float b) {
  unsigned r;
  asm("v_cvt_pk_bf16_f32 %0, %1, %2" : "=v"(r) : "v"(a), "v"(b));
  return r;
}
__device__ __forceinline__ unsigned cvtpk_h(float a, float b) {
  union { fp16x2 h; unsigned u; } r;
  r.h = __builtin_amdgcn_cvt_pkrtz(a, b);
  return r.u;
}
__device__ __forceinline__ float fexp2(float x) {
  float r;
  asm("v_exp_f32 %0, %1" : "=v"(r) : "v"(x));
  return r;
}
__device__ __forceinline__ void pl32swap(unsigned& a, unsigned& b) {
  asm("v_permlane32_swap_b32 %0, %1" : "+v"(a), "+v"(b));
}

// One merged prep kernel (3072 blocks):
//  b in [0,1024):    q (D x SQ) -> QT (SQ x D) f16, scaled by log2e
//  b in [1024,2048): k (D x SKV) -> PK packed A-frag order (32-kv tiles)
//  b in [2048,3072): v (D x SKV) -> PV packed A-frag order (32-kv tiles)
__global__ void prep_all(const float* __restrict__ q, const float* __restrict__ k,
                         const float* __restrict__ v,
                         _Float16* __restrict__ QT, _Float16* __restrict__ PK,
                         _Float16* __restrict__ PV) {
  __shared__ float tile[32][33];
  int b = blockIdx.x;
  int t = threadIdx.x, g = t >> 5, l = t & 31;
  if (b < 2048) {
    const bool isQ = (b < 1024);
    int bb = isQ ? b : b - 1024;
    int s0 = (bb & 255) * 32, d0 = (bb >> 8) * 32;
    const float* src = isQ ? q : k;
#pragma unroll
    for (int j = 0; j < 4; ++j)
      tile[g * 4 + j][l] = src[(size_t)(d0 + g * 4 + j) * SQ + s0 + l];
    __syncthreads();
    if (isQ) {
#pragma unroll
      for (int j = 0; j < 4; ++j) {
        int sl = g * 4 + j;
        QT[(size_t)(s0 + sl) * D + d0 + l] = (_Float16)(tile[l][sl] * LOG2E);
      }
    } else {
#pragma unroll
      for (int j = 0; j < 4; ++j) {
        int srow = s0 + g * 4 + j;
        int dcol = d0 + l;
        size_t elem = (size_t)(srow >> 5) * 4096 + (size_t)(dcol >> 4) * 512 +
                      (((dcol >> 3) & 1) * 32 + (srow & 31)) * 8 + (dcol & 7);
        PK[elem] = (_Float16)tile[l][g * 4 + j];
      }
    }
  } else {
    int i4 = ((b - 2048) * 256 + t) * 4;
    float4 x = *(const float4*)(v + i4);
    int drow = i4 >> 13;          // / SKV
    int kv = i4 & (SKV - 1);
    size_t elem = (size_t)(kv >> 5) * 4096 +
                  (size_t)((drow >> 5) * 2 + ((kv >> 4) & 1)) * 512 +
                  (((kv >> 3) & 1) * 32 + (drow & 31)) * 8 + (kv & 7);
    half4v o = { (_Float16)x.x, (_Float16)x.y, (_Float16)x.z, (_Float16)x.w };
    *(half4v*)(PV + elem) = o;
  }
}

// Flash, LDS-multicast K/V, BKV=32, 32KB LDS -> 4 independent blocks/CU
// (4 waves/SIMD phase diversity). One barrier per step, K/V double-buffered,
// next-step stage issued at step top. 1D grid with XCD-affinity decode:
// xcd = bid&7 serves splits [xcd*spx, (xcd+1)*spx) -> per-XCD L2 working set
// = Q (2MB) + 2 splits' K/V slices (~0.5MB) < 4MB (fixes r13's 157MB FETCH).
__global__ __launch_bounds__(256, 4)
void flash_fwd(const _Float16* __restrict__ QT, const _Float16* __restrict__ PK,
               const _Float16* __restrict__ PV,
               ushort* __restrict__ Opart, float* __restrict__ Mst,
               float* __restrict__ Lst, int splitLen, int nsplit) {
  __shared__ _Float16 Kl[2][BKV * D];   // 8 KB per buffer
  __shared__ _Float16 Vl[2][BKV * D];   // 8 KB per buffer

  const int tid = threadIdx.x;
  const int w = tid >> 6;
  const int lane = tid & 63;
  const int lc = lane & 31;
  const int hi = lane >> 5;

  // XCD-affinity decode (T1): consecutive-split blocks share an XCD's L2
  const int bid = blockIdx.x;
  const int xcd = bid & 7;
  const int idx = bid >> 3;
  const int spx = nsplit >> 3;                 // splits per XCD (nsplit % 8 == 0)
  const int split = xcd * spx + (idx >> 6);
  const int qb = idx & 63;

  const int qrow = qb * BQ + w * 32 + lc;

  // Q B-frags (col = q = lc, k-dim = d), pre-scaled by log2e
  half8 qh[8];
#pragma unroll
  for (int ds = 0; ds < 8; ++ds)
    qh[ds] = *(const half8*)(QT + (size_t)qrow * D + ds * 16 + hi * 8);

  f32x16 Ot[4];
#pragma unroll
  for (int dt = 0; dt < 4; ++dt)
#pragma unroll
    for (int e = 0; e < 16; ++e) Ot[dt][e] = 0.f;
  float mrun = -INFINITY, lrun = 0.f;

  const int kvBase = split * splitLen;
  const int nsteps = splitLen / BKV;
  const int tBase = kvBase / BKV;

  // ---- staging: K+V tile = 16 x 1KB chunks, 4 per wave; linear LDS dest ----
#define STAGE(NB, T)                                                          \
  {                                                                           \
    _Pragma("unroll")                                                         \
    for (int j = 0; j < 4; ++j) {                                             \
      int cc = w * 4 + j;                                                     \
      int c8 = cc & 7;                                                        \
      const _Float16* gp = ((cc < 8) ? PK : PV) +                             \
                           (size_t)(T) * (BKV * D) + c8 * 512 + lane * 8;     \
      _Float16* lp = ((cc < 8) ? &Kl[NB][0] : &Vl[NB][0]) + c8 * 512;         \
      __builtin_amdgcn_global_load_lds(                                       \
          (const __attribute__((address_space(1))) unsigned*)gp,              \
          (__attribute__((address_space(3))) unsigned*)lp, 16, 0, 0);         \
    }                                                                         \
  }

  STAGE(0, tBase);
  __syncthreads();
  int cur = 0;

  for (int it = 0; it < nsteps; ++it) {
    const bool more = (it + 1 < nsteps);
    if (more) STAGE(cur ^ 1, tBase + it + 1);   // in flight across whole step

    const _Float16* kb = &Kl[cur][0] + lane * 8;
    const _Float16* vb = &Vl[cur][0] + lane * 8;

    // ---- K frags from LDS + QK MFMAs (single 32x32 S^T tile) ----
    half8 ka[8];
#pragma unroll
    for (int j = 0; j < 8; ++j) ka[j] = *(const half8*)(kb + j * 512);

    f32x16 s0;
#pragma unroll
    for (int e = 0; e < 16; ++e) s0[e] = 0.f;
    __builtin_amdgcn_s_setprio(1);
#pragma unroll
    for (int ds = 0; ds < 8; ++ds)
      s0 = __builtin_amdgcn_mfma_f32_32x32x16_f16(ka[ds], qh[ds], s0, 0, 0, 0);
    __builtin_amdgcn_s_setprio(0);

    // ---- V frags issued now; lgkm latency hides under softmax ----
    half8 va[8];
#pragma unroll
    for (int f = 0; f < 8; ++f) va[f] = *(const half8*)(vb + f * 512);

    // ---- in-register online softmax (exp2 domain), tree reductions ----
    float t4a = fmaxf(fmaxf(s0[0], s0[4]), fmaxf(s0[8], s0[12]));
    float t4b = fmaxf(fmaxf(s0[1], s0[5]), fmaxf(s0[9], s0[13]));
    float t4c = fmaxf(fmaxf(s0[2], s0[6]), fmaxf(s0[10], s0[14]));
    float t4d = fmaxf(fmaxf(s0[3], s0[7]), fmaxf(s0[11], s0[15]));
    float mx = fmaxf(fmaxf(t4a, t4b), fmaxf(t4c, t4d));
    mx = fmaxf(mx, __shfl_xor(mx, 32));

    if (!__all(mx - mrun <= DEFER_THR)) {     // defer-max (T13)
      float mn = fmaxf(mrun, mx);
      float sc = fexp2(mrun - mn);            // first iter: exp2(-inf)=0
      mrun = mn;
      lrun *= sc;
#pragma unroll
      for (int dt = 0; dt < 4; ++dt)
#pragma unroll
        for (int e = 0; e < 16; ++e) Ot[dt][e] *= sc;
    }

#pragma unroll
    for (int e = 0; e < 16; ++e) s0[e] = fexp2(s0[e] - mrun);
    float a4a = (s0[0] + s0[4]) + (s0[8] + s0[12]);
    float a4b = (s0[1] + s0[5]) + (s0[9] + s0[13]);
    float a4c = (s0[2] + s0[6]) + (s0[10] + s0[14]);
    float a4d = (s0[3] + s0[7]) + (s0[11] + s0[15]);
    float lsum = (a4a + a4b) + (a4c + a4d);
    lsum += __shfl_xor(lsum, 32);
    lrun += lsum;

    // ---- P -> f16 B-frags in-register (T12: cvt_pkrtz + permlane32_swap) ----
    unsigned pk[8];
    half8 pb[2];
    union { unsigned u[4]; half8 v; } pbu;
#pragma unroll
    for (int j = 0; j < 8; ++j) pk[j] = cvtpk_h(s0[2 * j], s0[2 * j + 1]);
    pl32swap(pk[0], pk[2]); pl32swap(pk[1], pk[3]);
    pl32swap(pk[4], pk[6]); pl32swap(pk[5], pk[7]);
    pbu.u[0] = pk[0]; pbu.u[1] = pk[1]; pbu.u[2] = pk[2]; pbu.u[3] = pk[3]; pb[0] = pbu.v;
    pbu.u[0] = pk[4]; pbu.u[1] = pk[5]; pbu.u[2] = pk[6]; pbu.u[3] = pk[7]; pb[1] = pbu.v;

    // ---- PV: O^T += V^T P^T (2 k-slices x 4 d-tiles) ----
    __builtin_amdgcn_s_setprio(1);
#pragma unroll
    for (int dt = 0; dt < 4; ++dt) {
      Ot[dt] = __builtin_amdgcn_mfma_f32_32x32x16_f16(va[dt * 2 + 0], pb[0], Ot[dt], 0, 0, 0);
      Ot[dt] = __builtin_amdgcn_mfma_f32_32x32x16_f16(va[dt * 2 + 1], pb[1], Ot[dt], 0, 0, 0);
    }
    __builtin_amdgcn_s_setprio(0);

    __syncthreads();   // staged tile landed; all reads of cur done -> safe swap
    cur ^= 1;
  }

  // ---- epilogue: bf16 partials; d = dt*32 + rg*8 + hi*4 + e ----
  ushort* Op = Opart + (size_t)split * SQ * D + (size_t)qrow * D;
#pragma unroll
  for (int dt = 0; dt < 4; ++dt) {
#pragma unroll
    for (int rg = 0; rg < 4; ++rg) {
      uint2 o2;
      o2.x = cvtpk_bf(Ot[dt][4 * rg + 0], Ot[dt][4 * rg + 1]);
      o2.y = cvtpk_bf(Ot[dt][4 * rg + 2], Ot[dt][4 * rg + 3]);
      *(uint2*)(Op + dt * 32 + rg * 8 + hi * 4) = o2;
    }
  }
  if (hi == 0) {
    Mst[split * SQ + qrow] = mrun;   // log2-domain
    Lst[split * SQ + qrow] = lrun;
  }
}

__global__ void combine(const ushort* __restrict__ Opart, const float* __restrict__ Mst,
                        const float* __restrict__ Lst, float* __restrict__ out, int nsplit) {
  int t4 = (blockIdx.x * 256 + threadIdx.x) * 4;
  int qi = t4 >> 7;
  float M = -INFINITY;
  for (int s = 0; s < nsplit; ++s) M = fmaxf(M, Mst[s * SQ + qi]);
  float n0 = 0.f, n1 = 0.f, n2 = 0.f, n3 = 0.f, den = 0.f;
  for (int s = 0; s < nsplit; ++s) {
    float wgt = fexp2(Mst[s * SQ + qi] - M);
    den += wgt * Lst[s * SQ + qi];
    ushort4 u = *(const ushort4*)(Opart + (size_t)s * SQ * D + t4);
    n0 += wgt * bf2f(u.x); n1 += wgt * bf2f(u.y);
    n2 += wgt * bf2f(u.z); n3 += wgt * bf2f(u.w);
  }
  float inv = 1.0f / den;
  float4 o = { n0 * inv, n1 * inv, n2 * inv, n3 * inv };
  *(float4*)(out + t4) = o;
}

extern "C" void kernel_launch(void* const* d_in, const int* in_sizes, int n_in,
                              void* d_out, int out_size, void* d_ws, size_t ws_size,
                              hipStream_t stream) {
  const float* q = (const float*)d_in[0];
  const float* k = (const float*)d_in[1];
  const float* v = (const float*)d_in[2];
  float* out = (float*)d_out;

  char* ws = (char*)d_ws;
  const size_t mat = (size_t)SQ * D * 2;   // 2 MB per f16 matrix
  _Float16* QT = (_Float16*)(ws);
  _Float16* PK = (_Float16*)(ws + mat);
  _Float16* PV = (_Float16*)(ws + 2 * mat);
  char* rest = ws + 3 * mat;

  const size_t opartSz = (size_t)SQ * D * 2;  // bf16 partials: 2 MB per split
  const size_t statSz  = (size_t)SQ * 4;
  int nsplit = 16;   // grid 1024 blocks = 4 resident/CU; XCD gets 2 splits
  while (nsplit > 8 &&
         3 * mat + (size_t)nsplit * (opartSz + 2 * statSz) > ws_size) nsplit >>= 1;

  ushort* Opart = (ushort*)rest;
  float* Mst = (float*)(rest + (size_t)nsplit * opartSz);
  float* Lst = (float*)(rest + (size_t)nsplit * opartSz + (size_t)nsplit * statSz);

  prep_all<<<3072, 256, 0, stream>>>(q, k, v, QT, PK, PV);
  flash_fwd<<<64 * nsplit, 256, 0, stream>>>(QT, PK, PV, Opart, Mst, Lst,
                                             SKV / nsplit, nsplit);
  combine<<<(SQ * D) / (256 * 4), 256, 0, stream>>>(Opart, Mst, Lst, out, nsplit);
}

// Round 16
// 60.307 us; speedup vs baseline: 1.8115x; 1.8115x over previous
//
#include <hip/hip_runtime.h>
#include <hip/hip_bf16.h>
#include <math.h>

typedef _Float16 half8 __attribute__((ext_vector_type(8)));
typedef __fp16 fp16x2 __attribute__((ext_vector_type(2)));
typedef float f32x4 __attribute__((ext_vector_type(4)));
typedef float f32x16 __attribute__((ext_vector_type(16)));

#define D 128
#define SQ 8192
#define SKV 8192
#define BQ 128    // q-rows per block (4 waves x 32)
#define BKV 64
#define LOG2E 1.4426950408889634f
#define DEFER_THR 11.5417f   // 8 * log2(e); P <= 2^11.54 ~ 2981 < f16 max

__device__ __forceinline__ ushort f2bf(float x) {
  union { float f; unsigned u; } v; v.f = x;
  unsigned r = v.u + 0x7fffu + ((v.u >> 16) & 1u);
  return (ushort)(r >> 16);
}
__device__ __forceinline__ float bf2f(ushort h) {
  union { unsigned u; float f; } v; v.u = ((unsigned)h) << 16;
  return v.f;
}
__device__ __forceinline__ unsigned cvtpk_bf(float a, float b) {
  unsigned r;
  asm("v_cvt_pk_bf16_f32 %0, %1, %2" : "=v"(r) : "v"(a), "v"(b));
  return r;
}
__device__ __forceinline__ unsigned cvtpk_h(float a, float b) {
  union { fp16x2 h; unsigned u; } r;
  r.h = __builtin_amdgcn_cvt_pkrtz(a, b);
  return r.u;
}
__device__ __forceinline__ float fexp2(float x) {
  float r;
  asm("v_exp_f32 %0, %1" : "=v"(r) : "v"(x));
  return r;
}
__device__ __forceinline__ void pl32swap(unsigned& a, unsigned& b) {
  asm("v_permlane32_swap_b32 %0, %1" : "+v"(a), "+v"(b));
}

// Merged, vectorized prep (1024 blocks):
//  b <  256: q (D x SQ) -> QT (SQ x D) f16 (x log2e); 32-s slab, all 128 d
//  b <  512: k (D x SKV) -> PK packed A-frag order (64-kv tiles)
//  b < 1024: v (D x SKV) -> PV packed A-frag order (64-kv tiles), pure relabel
__global__ void prep_all(const float* __restrict__ q, const float* __restrict__ k,
                         const float* __restrict__ v,
                         _Float16* __restrict__ QT, _Float16* __restrict__ PK,
                         _Float16* __restrict__ PV) {
  int b = blockIdx.x;
  int t = threadIdx.x;
  if (b < 512) {
    const bool isQ = (b < 256);
    const float* src = isQ ? q : k;
    const float scl = isQ ? LOG2E : 1.0f;
    int s0 = (isQ ? b : b - 256) * 32;
    __shared__ float lds[128][33];
    int dr = t >> 5, l = t & 31;
#pragma unroll
    for (int j = 0; j < 16; ++j) {
      int dd = dr * 16 + j;
      lds[dd][l] = src[(size_t)dd * SQ + s0 + l];
    }
    __syncthreads();
#pragma unroll
    for (int i = 0; i < 2; ++i) {
      int cid = t + i * 256;        // 0..511
      int c = cid >> 5, sl = cid & 31;
      half8 hv;
#pragma unroll
      for (int e = 0; e < 8; ++e) hv[e] = (_Float16)(lds[c * 8 + e][sl] * scl);
      if (isQ) {
        *(half8*)(QT + (size_t)(s0 + sl) * D + c * 8) = hv;
      } else {
        int srow = s0 + sl;
        size_t elem = (size_t)((srow >> 5) * 8 + (c >> 1)) * 512 +
                      ((c & 1) * 32 + (srow & 31)) * 8;
        *(half8*)(PK + elem) = hv;
      }
    }
  } else {
    int idx = (b - 512) * 256 + t;
    int i8 = idx * 8;
    float4 x0 = *(const float4*)(v + i8);
    float4 x1 = *(const float4*)(v + i8 + 4);
    int drow = i8 >> 13;          // / SKV
    int kv = i8 & (SKV - 1);
    size_t elem = (size_t)(kv >> 6) * 8192 +
                  (size_t)((drow >> 5) * 4 + ((kv >> 4) & 3)) * 512 +
                  (((kv >> 3) & 1) * 32 + (drow & 31)) * 8;
    half8 hv = { (_Float16)x0.x, (_Float16)x0.y, (_Float16)x0.z, (_Float16)x0.w,
                 (_Float16)x1.x, (_Float16)x1.y, (_Float16)x1.z, (_Float16)x1.w };
    *(half8*)(PV + elem) = hv;
  }
}

// r11 flash (proven 50us): LDS-multicast K/V via global_load_lds (linear dest,
// packed source), double-buffered, one barrier per step, V frags issued early.
// NEW: anti-phase stagger — half the blocks sleep ~half a step at launch so
// co-resident block pairs run MFMA against each other's softmax.
__global__ __launch_bounds__(256, 2)
void flash_fwd(const _Float16* __restrict__ QT, const _Float16* __restrict__ PK,
               const _Float16* __restrict__ PV,
               ushort* __restrict__ Opart, float* __restrict__ Mst,
               float* __restrict__ Lst, int splitLen) {
  __shared__ _Float16 Kl[2][BKV * D];   // 16 KB per buffer
  __shared__ _Float16 Vl[2][BKV * D];

  // temporal desync: presumed co-resident pairing (id, id+256) differs in y>=4
  if (blockIdx.y & 4) __builtin_amdgcn_s_sleep(60);   // ~3840 cyc

  const int tid = threadIdx.x;
  const int w = tid >> 6;
  const int lane = tid & 63;
  const int lc = lane & 31;
  const int hi = lane >> 5;
  const int qb = blockIdx.x;
  const int split = blockIdx.y;
  const int qrow = qb * BQ + w * 32 + lc;

  // Q B-frags (col = q = lc, k-dim = d), pre-scaled by log2e
  half8 qh[8];
#pragma unroll
  for (int ds = 0; ds < 8; ++ds)
    qh[ds] = *(const half8*)(QT + (size_t)qrow * D + ds * 16 + hi * 8);

  f32x16 Ot[4];
#pragma unroll
  for (int dt = 0; dt < 4; ++dt)
#pragma unroll
    for (int e = 0; e < 16; ++e) Ot[dt][e] = 0.f;
  float mrun = -INFINITY, lrun = 0.f;

  const int kvBase = split * splitLen;
  const int nsteps = splitLen / BKV;

#define STAGE(NB, KV0)                                                        \
  {                                                                           \
    _Pragma("unroll")                                                         \
    for (int j = 0; j < 8; ++j) {                                             \
      int cblk = w * 8 + j;                                                   \
      int cc = cblk & 15;                                                     \
      const _Float16* gp = ((cblk < 16) ? PK : PV) +                          \
                           (size_t)(KV0) * D + cc * 512 + lane * 8;           \
      _Float16* lp = ((cblk < 16) ? &Kl[NB][0] : &Vl[NB][0]) + cc * 512;      \
      __builtin_amdgcn_global_load_lds(                                       \
          (const __attribute__((address_space(1))) unsigned*)gp,              \
          (__attribute__((address_space(3))) unsigned*)lp, 16, 0, 0);         \
    }                                                                         \
  }

  STAGE(0, kvBase);
  __syncthreads();
  int cur = 0;

  for (int it = 0; it < nsteps; ++it) {
    const int kv0 = kvBase + it * BKV;
    const bool more = (it + 1 < nsteps);
    if (more) STAGE(cur ^ 1, kv0 + BKV);   // in flight across the whole step

    const _Float16* kb = &Kl[cur][0] + lane * 8;
    const _Float16* vb = &Vl[cur][0] + lane * 8;

    // ---- K frags from LDS + QK MFMAs ----
    half8 ka[16];
#pragma unroll
    for (int j = 0; j < 16; ++j) ka[j] = *(const half8*)(kb + j * 512);

    f32x16 s0, s1;
#pragma unroll
    for (int e = 0; e < 16; ++e) { s0[e] = 0.f; s1[e] = 0.f; }
    __builtin_amdgcn_s_setprio(1);
#pragma unroll
    for (int ds = 0; ds < 8; ++ds) {
      s0 = __builtin_amdgcn_mfma_f32_32x32x16_f16(ka[ds], qh[ds], s0, 0, 0, 0);
      s1 = __builtin_amdgcn_mfma_f32_32x32x16_f16(ka[8 + ds], qh[ds], s1, 0, 0, 0);
    }
    __builtin_amdgcn_s_setprio(0);

    // ---- V frags issued now; lgkm latency hides under softmax ----
    half8 va[16];
#pragma unroll
    for (int f = 0; f < 16; ++f) va[f] = *(const half8*)(vb + f * 512);

    // ---- in-register online softmax (exp2 domain), tree reductions ----
    float t8[8];
#pragma unroll
    for (int e = 0; e < 8; ++e)
      t8[e] = fmaxf(fmaxf(s0[e], s0[e + 8]), fmaxf(s1[e], s1[e + 8]));
    float mx = fmaxf(fmaxf(fmaxf(t8[0], t8[4]), fmaxf(t8[1], t8[5])),
                     fmaxf(fmaxf(t8[2], t8[6]), fmaxf(t8[3], t8[7])));
    mx = fmaxf(mx, __shfl_xor(mx, 32));

    if (!__all(mx - mrun <= DEFER_THR)) {     // defer-max (T13)
      float mn = fmaxf(mrun, mx);
      float sc = fexp2(mrun - mn);            // first iter: exp2(-inf)=0
      mrun = mn;
      lrun *= sc;
#pragma unroll
      for (int dt = 0; dt < 4; ++dt)
#pragma unroll
        for (int e = 0; e < 16; ++e) Ot[dt][e] *= sc;
    }

#pragma unroll
    for (int e = 0; e < 16; ++e) {
      s0[e] = fexp2(s0[e] - mrun);
      s1[e] = fexp2(s1[e] - mrun);
    }
    float a8[8];
#pragma unroll
    for (int e = 0; e < 8; ++e) a8[e] = (s0[e] + s0[e + 8]) + (s1[e] + s1[e + 8]);
    float lsum = ((a8[0] + a8[4]) + (a8[1] + a8[5])) +
                 ((a8[2] + a8[6]) + (a8[3] + a8[7]));
    lsum += __shfl_xor(lsum, 32);
    lrun += lsum;

    // ---- P -> f16 B-frags in-register (T12: cvt_pkrtz + permlane32_swap) ----
    unsigned pk[8];
    half8 pb[4];
    union { unsigned u[4]; half8 v; } pbu;
#pragma unroll
    for (int j = 0; j < 8; ++j) pk[j] = cvtpk_h(s0[2 * j], s0[2 * j + 1]);
    pl32swap(pk[0], pk[2]); pl32swap(pk[1], pk[3]);
    pl32swap(pk[4], pk[6]); pl32swap(pk[5], pk[7]);
    pbu.u[0] = pk[0]; pbu.u[1] = pk[1]; pbu.u[2] = pk[2]; pbu.u[3] = pk[3]; pb[0] = pbu.v;
    pbu.u[0] = pk[4]; pbu.u[1] = pk[5]; pbu.u[2] = pk[6]; pbu.u[3] = pk[7]; pb[1] = pbu.v;
#pragma unroll
    for (int j = 0; j < 8; ++j) pk[j] = cvtpk_h(s1[2 * j], s1[2 * j + 1]);
    pl32swap(pk[0], pk[2]); pl32swap(pk[1], pk[3]);
    pl32swap(pk[4], pk[6]); pl32swap(pk[5], pk[7]);
    pbu.u[0] = pk[0]; pbu.u[1] = pk[1]; pbu.u[2] = pk[2]; pbu.u[3] = pk[3]; pb[2] = pbu.v;
    pbu.u[0] = pk[4]; pbu.u[1] = pk[5]; pbu.u[2] = pk[6]; pbu.u[3] = pk[7]; pb[3] = pbu.v;

    // ---- PV: O^T += V^T P^T ----
    __builtin_amdgcn_s_setprio(1);
#pragma unroll
    for (int cc = 0; cc < 4; ++cc) {
      Ot[0] = __builtin_amdgcn_mfma_f32_32x32x16_f16(va[0 * 4 + cc], pb[cc], Ot[0], 0, 0, 0);
      Ot[1] = __builtin_amdgcn_mfma_f32_32x32x16_f16(va[1 * 4 + cc], pb[cc], Ot[1], 0, 0, 0);
      Ot[2] = __builtin_amdgcn_mfma_f32_32x32x16_f16(va[2 * 4 + cc], pb[cc], Ot[2], 0, 0, 0);
      Ot[3] = __builtin_amdgcn_mfma_f32_32x32x16_f16(va[3 * 4 + cc], pb[cc], Ot[3], 0, 0, 0);
    }
    __builtin_amdgcn_s_setprio(0);

    __syncthreads();   // staged tile landed; all reads of cur done -> safe swap
    cur ^= 1;
  }

  // ---- epilogue: bf16 partials; d = dt*32 + rg*8 + hi*4 + e ----
  ushort* Op = Opart + (size_t)split * SQ * D + (size_t)qrow * D;
#pragma unroll
  for (int dt = 0; dt < 4; ++dt) {
#pragma unroll
    for (int rg = 0; rg < 4; ++rg) {
      uint2 o2;
      o2.x = cvtpk_bf(Ot[dt][4 * rg + 0], Ot[dt][4 * rg + 1]);
      o2.y = cvtpk_bf(Ot[dt][4 * rg + 2], Ot[dt][4 * rg + 3]);
      *(uint2*)(Op + dt * 32 + rg * 8 + hi * 4) = o2;
    }
  }
  if (hi == 0) {
    Mst[split * SQ + qrow] = mrun;   // log2-domain
    Lst[split * SQ + qrow] = lrun;
  }
}

__global__ void combine(const ushort* __restrict__ Opart, const float* __restrict__ Mst,
                        const float* __restrict__ Lst, float* __restrict__ out, int nsplit) {
  int t4 = (blockIdx.x * 256 + threadIdx.x) * 4;
  int qi = t4 >> 7;
  float M = -INFINITY;
  for (int s = 0; s < nsplit; ++s) M = fmaxf(M, Mst[s * SQ + qi]);
  float n0 = 0.f, n1 = 0.f, n2 = 0.f, n3 = 0.f, den = 0.f;
  for (int s = 0; s < nsplit; ++s) {
    float wgt = fexp2(Mst[s * SQ + qi] - M);
    den += wgt * Lst[s * SQ + qi];
    ushort4 u = *(const ushort4*)(Opart + (size_t)s * SQ * D + t4);
    n0 += wgt * bf2f(u.x); n1 += wgt * bf2f(u.y);
    n2 += wgt * bf2f(u.z); n3 += wgt * bf2f(u.w);
  }
  float inv = 1.0f / den;
  float4 o = { n0 * inv, n1 * inv, n2 * inv, n3 * inv };
  *(float4*)(out + t4) = o;
}

extern "C" void kernel_launch(void* const* d_in, const int* in_sizes, int n_in,
                              void* d_out, int out_size, void* d_ws, size_t ws_size,
                              hipStream_t stream) {
  const float* q = (const float*)d_in[0];
  const float* k = (const float*)d_in[1];
  const float* v = (const float*)d_in[2];
  float* out = (float*)d_out;

  char* ws = (char*)d_ws;
  const size_t mat = (size_t)SQ * D * 2;   // 2 MB per f16 matrix
  _Float16* QT = (_Float16*)(ws);
  _Float16* PK = (_Float16*)(ws + mat);
  _Float16* PV = (_Float16*)(ws + 2 * mat);
  char* rest = ws + 3 * mat;

  const size_t opartSz = (size_t)SQ * D * 2;  // bf16 partials: 2 MB per split
  const size_t statSz  = (size_t)SQ * 4;
  int nsplit = 8;    // grid 64 x 8 = 512 blocks = 2 resident/CU, single pass
  while (nsplit > 1 &&
         3 * mat + (size_t)nsplit * (opartSz + 2 * statSz) > ws_size) nsplit >>= 1;

  ushort* Opart = (ushort*)rest;
  float* Mst = (float*)(rest + (size_t)nsplit * opartSz);
  float* Lst = (float*)(rest + (size_t)nsplit * opartSz + (size_t)nsplit * statSz);

  prep_all<<<1024, 256, 0, stream>>>(q, k, v, QT, PK, PV);
  flash_fwd<<<dim3(SQ / BQ, nsplit), 256, 0, stream>>>(QT, PK, PV,
                                                       Opart, Mst, Lst, SKV / nsplit);
  combine<<<(SQ * D) / (256 * 4), 256, 0, stream>>>(Opart, Mst, Lst, out, nsplit);
}